// Round 20
// baseline (226.429 us; speedup 1.0000x reference)
//
#include <hip/hip_runtime.h>
#include <hip/hip_bf16.h>

using bf16x8 = __attribute__((ext_vector_type(8))) short;
using f32x4  = __attribute__((ext_vector_type(4))) float;

__device__ __forceinline__ unsigned short f32_to_bf16(float f) {
  unsigned u = __float_as_uint(f);
  u += 0x7FFFu + ((u >> 16) & 1u);   // RNE
  return (unsigned short)(u >> 16);
}
__device__ __forceinline__ unsigned pack2(float lo, float hi) {
  __hip_bfloat162 h = __float22bfloat162_rn(make_float2(lo, hi)); // v_cvt_pk path
  return *reinterpret_cast<unsigned*>(&h);
}
__device__ __forceinline__ void gload_lds16(const void* g, void* l) {
  __builtin_amdgcn_global_load_lds(
      (const __attribute__((address_space(1))) unsigned int*)g,
      (__attribute__((address_space(3))) unsigned int*)l, 16, 0, 0);
}

// ---------------- segmented cast: all five f32->bf16 conversions in one launch ----------------
__global__ void cast_all_kernel(const float* __restrict__ wq, const float* __restrict__ wo,
                                const float* __restrict__ wk, const float* __restrict__ wv,
                                const float* __restrict__ x,
                                unsigned short* __restrict__ WQKV,
                                unsigned short* __restrict__ WO,
                                unsigned short* __restrict__ XBF) {
  int i = blockIdx.x * blockDim.x + threadIdx.x;   // float4 index
  const float4* s; ushort4* d; int j;
  if (i < 1048576)      { s = (const float4*)wq; d = (ushort4*)WQKV;            j = i; }
  else if (i < 2097152) { s = (const float4*)wo; d = (ushort4*)WO;              j = i - 1048576; }
  else if (i < 2359296) { s = (const float4*)wk; d = (ushort4*)WQKV + 1048576;  j = i - 2097152; }
  else if (i < 2621440) { s = (const float4*)wv; d = (ushort4*)WQKV + 1310720;  j = i - 2359296; }
  else                  { s = (const float4*)x;  d = (ushort4*)XBF;             j = i - 2621440; }
  float4 v = s[j];
  ushort4 o;
  o.x = f32_to_bf16(v.x); o.y = f32_to_bf16(v.y);
  o.z = f32_to_bf16(v.z); o.w = f32_to_bf16(v.w);
  d[j] = o;
}

// ---------------- GEMM v2: C[M,N] = A[M,K] * W[N,K]^T ----------------
// MODE 0: plain f32 C.  MODE 1 (QKV, BM=256): Q-tiles (bn<8) -> bf16 QBF (ld 2048),
// KV-tiles (bn>=8) -> f32 XKV (ld 1024).
template <int BM, int MODE>
__global__ __launch_bounds__(512, 2) void gemm256_kernel(
    const unsigned short* __restrict__ A, const unsigned short* __restrict__ Bw,
    float* __restrict__ C, unsigned short* __restrict__ qbf_out,
    float* __restrict__ xkv_out, int M, int N, int K) {
  constexpr int ABYTES = BM * 128;
  constexpr int BBYTES = 256 * 128;
  constexpr int BUFB   = ABYTES + BBYTES;
  constexpr int ALOADS = BM / 64;
  constexpr int WROWS  = BM / 32;
  __shared__ __align__(16) char Lsh[2 * BUFB];

  const int tid = threadIdx.x;
  const int wid = tid >> 6, lane = tid & 63;
  const int lr = lane & 15, lg = lane >> 4;
  const int wr = wid >> 2, wc = wid & 3;
  const int bn = blockIdx.x, bm = blockIdx.y;
  const int x0 = lg * 16;

  f32x4 acc[WROWS][4] = {};

  const char* Ag = (const char*)A + (size_t)(bm * BM) * K * 2;
  const char* Bg = (const char*)Bw + (size_t)(bn * 256) * K * 2;

  int aoff[ALOADS], boff[4];
#pragma unroll
  for (int i = 0; i < ALOADS; ++i) {
    int lin = wid * (BM * 16) + i * 1024 + lane * 16;
    int grow = lin >> 7;
    int gcol = (lin & 127) ^ ((grow & 7) << 4);
    aoff[i] = grow * (K * 2) + gcol;
  }
#pragma unroll
  for (int i = 0; i < 4; ++i) {
    int lin = wid * 4096 + i * 1024 + lane * 16;
    int grow = lin >> 7;
    int gcol = (lin & 127) ^ ((grow & 7) << 4);
    boff[i] = grow * (K * 2) + gcol;
  }

  auto stage = [&](int s, int buf) {
    const int kb = s * 128;
    char* Lb = Lsh + buf * BUFB;
#pragma unroll
    for (int i = 0; i < ALOADS; ++i)
      gload_lds16(Ag + aoff[i] + kb, Lb + wid * (BM * 16) + i * 1024);
#pragma unroll
    for (int i = 0; i < 4; ++i)
      gload_lds16(Bg + boff[i] + kb, Lb + ABYTES + wid * 4096 + i * 1024);
  };

  auto kstep = [&](char* Lb) {
    bf16x8 bfr[4][2];
#pragma unroll
    for (int fc = 0; fc < 4; ++fc) {
      const int row = wc * 64 + fc * 16 + lr;
      const int base = ABYTES + row * 128;
      const int sw = (row & 7) << 4;
#pragma unroll
      for (int ks = 0; ks < 2; ++ks)
        bfr[fc][ks] = *reinterpret_cast<const bf16x8*>(Lb + base + ((ks * 64 + x0) ^ sw));
    }
#pragma unroll
    for (int q = 0; q < WROWS / 2; ++q) {
      bf16x8 af[2][2];
#pragma unroll
      for (int t = 0; t < 2; ++t) {
        const int row = wr * (BM / 2) + (2 * q + t) * 16 + lr;
        const int base = row * 128;
        const int sw = (row & 7) << 4;
#pragma unroll
        for (int ks = 0; ks < 2; ++ks)
          af[t][ks] = *reinterpret_cast<const bf16x8*>(Lb + base + ((ks * 64 + x0) ^ sw));
      }
      asm volatile("s_waitcnt lgkmcnt(0)" ::: "memory");
      __builtin_amdgcn_sched_barrier(0);
      __builtin_amdgcn_s_setprio(1);
#pragma unroll
      for (int t = 0; t < 2; ++t)
#pragma unroll
        for (int fc = 0; fc < 4; ++fc) {
          acc[2 * q + t][fc] = __builtin_amdgcn_mfma_f32_16x16x32_bf16(af[t][0], bfr[fc][0], acc[2 * q + t][fc], 0, 0, 0);
          acc[2 * q + t][fc] = __builtin_amdgcn_mfma_f32_16x16x32_bf16(af[t][1], bfr[fc][1], acc[2 * q + t][fc], 0, 0, 0);
        }
      __builtin_amdgcn_s_setprio(0);
    }
  };

  const int NST = K >> 6;
  stage(0, 0);
  for (int it = 0; it < NST / 2; ++it) {
    __builtin_amdgcn_s_barrier();
    stage(2 * it + 1, 1);
    if constexpr (BM == 256) asm volatile("s_waitcnt vmcnt(8)" ::: "memory");
    else                     asm volatile("s_waitcnt vmcnt(6)" ::: "memory");
    __builtin_amdgcn_s_barrier();
    kstep(Lsh);
    __builtin_amdgcn_s_barrier();
    if (it < NST / 2 - 1) {
      stage(2 * it + 2, 0);
      if constexpr (BM == 256) asm volatile("s_waitcnt vmcnt(8)" ::: "memory");
      else                     asm volatile("s_waitcnt vmcnt(6)" ::: "memory");
    } else {
      asm volatile("s_waitcnt vmcnt(0)" ::: "memory");
    }
    __builtin_amdgcn_s_barrier();
    kstep(Lsh + BUFB);
  }

  if constexpr (MODE == 0) {
#pragma unroll
    for (int fr = 0; fr < WROWS; ++fr) {
      const int m = bm * BM + wr * (BM / 2) + fr * 16 + lg * 4;
#pragma unroll
      for (int fc = 0; fc < 4; ++fc) {
        const int n = bn * 256 + wc * 64 + fc * 16 + lr;
#pragma unroll
        for (int r = 0; r < 4; ++r)
          C[(size_t)(m + r) * N + n] = acc[fr][fc][r];
      }
    }
  } else {
    if (bn < 8) {           // Q tiles -> bf16, ld 2048
#pragma unroll
      for (int fr = 0; fr < WROWS; ++fr) {
        const int m = bm * BM + wr * (BM / 2) + fr * 16 + lg * 4;
#pragma unroll
        for (int fc = 0; fc < 4; ++fc) {
          const int n = bn * 256 + wc * 64 + fc * 16 + lr;
#pragma unroll
          for (int r = 0; r < 4; ++r)
            qbf_out[(size_t)(m + r) * 2048 + n] = f32_to_bf16(acc[fr][fc][r]);
        }
      }
    } else {                // KV tiles -> f32 compact, ld 1024
#pragma unroll
      for (int fr = 0; fr < WROWS; ++fr) {
        const int m = bm * BM + wr * (BM / 2) + fr * 16 + lg * 4;
#pragma unroll
        for (int fc = 0; fc < 4; ++fc) {
          const int n = bn * 256 + wc * 64 + fc * 16 + lr - 2048;
#pragma unroll
          for (int r = 0; r < 4; ++r)
            xkv_out[(size_t)(m + r) * 1024 + n] = acc[fr][fc][r];
        }
      }
    }
  }
}

// ---------------- merged K-RoPE + V pass, vectorized (float4 in/out) ----------------
__global__ void kv_proc_kernel(const float* __restrict__ xkv, const float* __restrict__ fc,
                               const float* __restrict__ fs, unsigned short* __restrict__ kbf,
                               float* __restrict__ keys, unsigned short* __restrict__ vt,
                               float* __restrict__ values) {
  int bid = blockIdx.x;
  if (bid < 2048) {
    // K path: thread handles 4 d's (2 RoPE pairs); i2 = d/4 in [0,32)
    int idx = bid * 256 + threadIdx.x;
    int i2 = idx & 31;
    int kvh = (idx >> 5) & 3;
    int l = (idx >> 7) & 2047;
    int b = idx >> 18;
    float4 t = reinterpret_cast<const float4*>(xkv)[(size_t)(b * 2048 + l) * 256 + kvh * 32 + i2];
    float2 c2 = reinterpret_cast<const float2*>(fc)[l * 32 + i2];
    float2 s2 = reinterpret_cast<const float2*>(fs)[l * 32 + i2];
    float4 r;
    r.x = t.x * c2.x - t.y * s2.x;
    r.y = t.x * s2.x + t.y * c2.x;
    r.z = t.z * c2.y - t.w * s2.y;
    r.w = t.z * s2.y + t.w * c2.y;
    ushort4 o;
    o.x = f32_to_bf16(r.x); o.y = f32_to_bf16(r.y);
    o.z = f32_to_bf16(r.z); o.w = f32_to_bf16(r.w);
    reinterpret_cast<ushort4*>(kbf)[((b * 4 + kvh) * 2048 + l) * 32 + i2] = o;
#pragma unroll
    for (int rep = 0; rep < 4; ++rep) {
      int h = kvh * 4 + rep;
      reinterpret_cast<float4*>(keys)[((size_t)(b * 16 + h) * 2048 + l) * 32 + i2] = r;
    }
  } else {
    // V path: thread handles 4 d's; dq = d/4 in [0,32)
    int idx = (bid - 2048) * 256 + threadIdx.x;
    int dq = idx & 31;
    int kvh = (idx >> 5) & 3;
    int l = (idx >> 7) & 2047;
    int b = idx >> 18;
    float4 v = reinterpret_cast<const float4*>(xkv)[(size_t)(b * 2048 + l) * 256 + 128 + kvh * 32 + dq];
#pragma unroll
    for (int rep = 0; rep < 4; ++rep) {
      int h = kvh * 4 + rep;
      reinterpret_cast<float4*>(values)[((size_t)(b * 16 + h) * 2048 + l) * 32 + dq] = v;
    }
    vt[((size_t)(b * 4 + kvh) * 128 + 4 * dq + 0) * 2048 + l] = f32_to_bf16(v.x);
    vt[((size_t)(b * 4 + kvh) * 128 + 4 * dq + 1) * 2048 + l] = f32_to_bf16(v.y);
    vt[((size_t)(b * 4 + kvh) * 128 + 4 * dq + 2) * 2048 + l] = f32_to_bf16(v.z);
    vt[((size_t)(b * 4 + kvh) * 128 + 4 * dq + 3) * 2048 + l] = f32_to_bf16(v.w);
  }
}

// ---------------- causal flash attention v14 (R16, measured 94.0us) ----------------
__global__ __launch_bounds__(256) void attn_kernel(
    const unsigned short* __restrict__ qbf, const float* __restrict__ fc,
    const float* __restrict__ fs, const unsigned short* __restrict__ kbf,
    const unsigned short* __restrict__ vt, unsigned short* __restrict__ obf) {
  __shared__ unsigned short Ks[64 * 128];      // [slot][d] rows 256B, XOR-swizzled, row-permuted
  __shared__ unsigned short Vs[128 * 64];      // [d][k] rows 128B, XOR-swizzled
  const int tid = threadIdx.x;
  const int w = tid >> 6, lane = tid & 63;
  const int lr = lane & 15, lg = lane >> 4;
  const int bid = blockIdx.x;
  const int qt = 15 - (bid >> 5);              // longest tiles dispatched first
  const int bh = bid & 31;
  const int b = bh >> 4, h = bh & 15, kv = h >> 2;
  const int q0 = qt * 128 + w * 32;
  const float ALPHA = 0.08838834764831845f;    // 1/sqrt(128), folded into Q
  const int swz = (lr & 7) << 4;

  // ---- fused RoPE Q-fragment build from bf16 Q ----
  bf16x8 qf[2][4];
#pragma unroll
  for (int t = 0; t < 2; ++t) {
    const int qrow = q0 + t * 16 + lr;
    const unsigned short* xqp = qbf + (size_t)(b * 2048 + qrow) * 2048 + h * 128;
    const float* fcp = fc + qrow * 64;
    const float* fsp = fs + qrow * 64;
#pragma unroll
    for (int s = 0; s < 4; ++s) {
      union { bf16x8 v8; unsigned short us[8]; } rw;
      rw.v8 = *reinterpret_cast<const bf16x8*>(xqp + s * 32 + lg * 8);
      float xv[8];
#pragma unroll
      for (int k = 0; k < 8; ++k) xv[k] = __uint_as_float(((unsigned)rw.us[k]) << 16);
      float4 c4 = *reinterpret_cast<const float4*>(fcp + s * 16 + lg * 4);
      float4 s4 = *reinterpret_cast<const float4*>(fsp + s * 16 + lg * 4);
      c4.x *= ALPHA; c4.y *= ALPHA; c4.z *= ALPHA; c4.w *= ALPHA;
      s4.x *= ALPHA; s4.y *= ALPHA; s4.z *= ALPHA; s4.w *= ALPHA;
      union { bf16x8 v8; unsigned u[4]; } uu;
      uu.u[0] = pack2(xv[0] * c4.x - xv[1] * s4.x, xv[0] * s4.x + xv[1] * c4.x);
      uu.u[1] = pack2(xv[2] * c4.y - xv[3] * s4.y, xv[2] * s4.y + xv[3] * c4.y);
      uu.u[2] = pack2(xv[4] * c4.z - xv[5] * s4.z, xv[4] * s4.z + xv[5] * c4.z);
      uu.u[3] = pack2(xv[6] * c4.w - xv[7] * s4.w, xv[6] * s4.w + xv[7] * c4.w);
      qf[t][s] = uu.v8;
    }
  }

  f32x4 acc[2][8] = {};
  float mrow[2] = {-1e30f, -1e30f}, lsum[2] = {0.f, 0.f};

  const char* kgbase = (const char*)(kbf + (size_t)(b * 4 + kv) * 2048 * 128);
  const char* vgbase = (const char*)(vt + (size_t)(b * 4 + kv) * 128 * 2048);

  int ksrc[4], vsrc[4];
#pragma unroll
  for (int i = 0; i < 4; ++i) {
    int p = w * 4096 + i * 1024 + lane * 16;
    int krow = p >> 8;
    int kperm = ((krow >> 5) << 5) + ((krow >> 4) & 1) + (((krow >> 2) & 3) << 3) + ((krow & 3) << 1);
    int kcol = (p & 255) ^ ((krow & 7) << 4);
    ksrc[i] = kperm * 256 + kcol;
    int drow = p >> 7;
    int dcol = (p & 127) ^ ((drow & 7) << 4);
    vsrc[i] = drow * 4096 + dcol;
  }

  const int nblocks = 2 * qt + 2;
  for (int j = 0; j < nblocks; ++j) {
    const int kb = j * 64;
    __syncthreads();
#pragma unroll
    for (int i = 0; i < 4; ++i) {
      gload_lds16(kgbase + (size_t)kb * 256 + ksrc[i], (char*)Ks + w * 4096 + i * 1024);
      gload_lds16(vgbase + (size_t)kb * 2 + vsrc[i], (char*)Vs + w * 4096 + i * 1024);
    }
    __syncthreads();
    if (j == nblocks - 1 && w < 2) continue;
    f32x4 sT[2][4];
#pragma unroll
    for (int c = 0; c < 4; ++c) {
      bf16x8 kf[4];
#pragma unroll
      for (int s = 0; s < 4; ++s)
        kf[s] = *reinterpret_cast<const bf16x8*>((char*)Ks + (((c * 16 + lr) * 256 + s * 64 + lg * 16) ^ swz));
      f32x4 t0 = {0.f, 0.f, 0.f, 0.f}, t1 = {0.f, 0.f, 0.f, 0.f};
#pragma unroll
      for (int s = 0; s < 4; ++s) {
        t0 = __builtin_amdgcn_mfma_f32_16x16x32_bf16(kf[s], qf[0][s], t0, 0, 0, 0);
        t1 = __builtin_amdgcn_mfma_f32_16x16x32_bf16(kf[s], qf[1][s], t1, 0, 0, 0);
      }
      sT[0][c] = t0; sT[1][c] = t1;
    }
    bf16x8 ptf[2][2];
#pragma unroll
    for (int t = 0; t < 2; ++t) {
      const int qrow = q0 + t * 16 + lr;
      float x[4][4];
      float mt = -1e30f;
#pragma unroll
      for (int c = 0; c < 4; ++c)
#pragma unroll
        for (int r = 0; r < 4; ++r) {
          int ka = kb + ((c >> 1) << 5) + (c & 1) + 8 * lg + 2 * r;
          float v = (ka <= qrow) ? sT[t][c][r] : -1e30f;
          x[c][r] = v;
          mt = fmaxf(mt, v);
        }
      mt = fmaxf(mt, __shfl_xor(mt, 16));
      mt = fmaxf(mt, __shfl_xor(mt, 32));
      const bool skip = __all(mt <= mrow[t] + 8.0f);
      float mnew, fac;
      if (skip) {
        mnew = mrow[t];
      } else {
        mnew = fmaxf(mrow[t], mt);
        fac = __expf(mrow[t] - mnew);
        mrow[t] = mnew;
      }
      float rs = 0.f;
      float pv[4][4];
#pragma unroll
      for (int c = 0; c < 4; ++c)
#pragma unroll
        for (int r = 0; r < 4; ++r) {
          float p = __expf(x[c][r] - mnew);
          pv[c][r] = p;
          rs += p;
        }
      rs += __shfl_xor(rs, 16);
      rs += __shfl_xor(rs, 32);
      if (skip) {
        lsum[t] += rs;
      } else {
        lsum[t] = lsum[t] * fac + rs;
#pragma unroll
        for (int dt = 0; dt < 8; ++dt)
#pragma unroll
          for (int r = 0; r < 4; ++r) acc[t][dt][r] *= fac;
      }
#pragma unroll
      for (int kk = 0; kk < 2; ++kk) {
        union { bf16x8 v8; unsigned u[4]; } uu;
#pragma unroll
        for (int wd = 0; wd < 4; ++wd)
          uu.u[wd] = pack2(pv[2 * kk][wd], pv[2 * kk + 1][wd]);
        ptf[t][kk] = uu.v8;
      }
    }
#pragma unroll
    for (int dt = 0; dt < 8; ++dt) {
      bf16x8 v0 = *reinterpret_cast<const bf16x8*>((char*)Vs + (((dt * 16 + lr) * 128 + lg * 16) ^ swz));
      bf16x8 v1 = *reinterpret_cast<const bf16x8*>((char*)Vs + (((dt * 16 + lr) * 128 + 64 + lg * 16) ^ swz));
      acc[0][dt] = __builtin_amdgcn_mfma_f32_16x16x32_bf16(v0, ptf[0][0], acc[0][dt], 0, 0, 0);
      acc[0][dt] = __builtin_amdgcn_mfma_f32_16x16x32_bf16(v1, ptf[0][1], acc[0][dt], 0, 0, 0);
      acc[1][dt] = __builtin_amdgcn_mfma_f32_16x16x32_bf16(v0, ptf[1][0], acc[1][dt], 0, 0, 0);
      acc[1][dt] = __builtin_amdgcn_mfma_f32_16x16x32_bf16(v1, ptf[1][1], acc[1][dt], 0, 0, 0);
    }
  }
#pragma unroll
  for (int t = 0; t < 2; ++t) {
    float inv = 1.0f / lsum[t];
#pragma unroll
    for (int dt = 0; dt < 8; ++dt) {
      ushort4 o;
      o.x = f32_to_bf16(acc[t][dt][0] * inv);
      o.y = f32_to_bf16(acc[t][dt][1] * inv);
      o.z = f32_to_bf16(acc[t][dt][2] * inv);
      o.w = f32_to_bf16(acc[t][dt][3] * inv);
      *reinterpret_cast<ushort4*>(obf + ((size_t)(b * 2048 + q0 + t * 16 + lr)) * 2048 + h * 128 + dt * 16 + lg * 4) = o;
    }
  }
}

// ---------------- host launch ----------------
extern "C" void kernel_launch(void* const* d_in, const int* in_sizes, int n_in,
                              void* d_out, int out_size, void* d_ws, size_t ws_size,
                              hipStream_t stream) {
  const float* x  = (const float*)d_in[0];
  const float* fc = (const float*)d_in[1];
  const float* fs = (const float*)d_in[2];
  const float* wq = (const float*)d_in[3];
  const float* wk = (const float*)d_in[4];
  const float* wv = (const float*)d_in[5];
  const float* wo = (const float*)d_in[6];

  float* out    = (float*)d_out;
  float* keys   = out + 8388608;
  float* values = out + 16777216;

  char* ws = (char*)d_ws;
  unsigned short* WQKV = (unsigned short*)(ws + 0);          // 12.6 MB: [wq;wk;wv] (3072 x 2048)
  unsigned short* WO   = (unsigned short*)(ws + 12582912);   // 8 MB
  unsigned short* XBF  = (unsigned short*)(ws + 20971520);   // 16 MB (reused as ATT)
  unsigned short* QBF  = (unsigned short*)(ws + 37748736);   // 16.8 MB bf16 Q (4096 x 2048)
  float*          XKV  = (float*)(ws + 54525952);            // 16.8 MB f32 KV (4096 x 1024)
  unsigned short* KBF  = (unsigned short*)(ws + 88080384);   // 4 MB
  unsigned short* VTB  = (unsigned short*)(ws + 92274688);   // 4 MB
  unsigned short* ATT  = XBF;                                // alias: XBF dead after projection

  cast_all_kernel<<<18432, 256, 0, stream>>>(wq, wo, wk, wv, x, WQKV, WO, XBF);

  // fused QKV projection (BM=256, 192 blocks, 1 round): Q->bf16 QBF, KV->f32 XKV
  gemm256_kernel<256, 1><<<dim3(12, 16), 512, 0, stream>>>(
      XBF, WQKV, nullptr, QBF, XKV, 4096, 3072, 2048);

  kv_proc_kernel<<<4096, 256, 0, stream>>>(XKV, fc, fs, KBF, keys, VTB, values);

  attn_kernel<<<512, 256, 0, stream>>>(QBF, fc, fs, KBF, VTB, ATT);

  // output projection (128x256 tiles, 256 blocks -> full fill)
  gemm256_kernel<128, 0><<<dim3(8, 32), 512, 0, stream>>>(
      ATT, WO, out, nullptr, nullptr, 4096, 2048, 2048);
}

// Round 21
// 222.617 us; speedup vs baseline: 1.0171x; 1.0171x over previous
//
#include <hip/hip_runtime.h>
#include <hip/hip_bf16.h>

using bf16x8 = __attribute__((ext_vector_type(8))) short;
using f32x4  = __attribute__((ext_vector_type(4))) float;

__device__ __forceinline__ unsigned short f32_to_bf16(float f) {
  unsigned u = __float_as_uint(f);
  u += 0x7FFFu + ((u >> 16) & 1u);   // RNE
  return (unsigned short)(u >> 16);
}
__device__ __forceinline__ unsigned pack2(float lo, float hi) {
  __hip_bfloat162 h = __float22bfloat162_rn(make_float2(lo, hi)); // v_cvt_pk path
  return *reinterpret_cast<unsigned*>(&h);
}
__device__ __forceinline__ void gload_lds16(const void* g, void* l) {
  __builtin_amdgcn_global_load_lds(
      (const __attribute__((address_space(1))) unsigned int*)g,
      (__attribute__((address_space(3))) unsigned int*)l, 16, 0, 0);
}

// ---------------- segmented cast: all five f32->bf16 conversions in one launch ----------------
__global__ void cast_all_kernel(const float* __restrict__ wq, const float* __restrict__ wo,
                                const float* __restrict__ wk, const float* __restrict__ wv,
                                const float* __restrict__ x,
                                unsigned short* __restrict__ WQKV,
                                unsigned short* __restrict__ WO,
                                unsigned short* __restrict__ XBF) {
  int i = blockIdx.x * blockDim.x + threadIdx.x;   // float4 index
  const float4* s; ushort4* d; int j;
  if (i < 1048576)      { s = (const float4*)wq; d = (ushort4*)WQKV;            j = i; }
  else if (i < 2097152) { s = (const float4*)wo; d = (ushort4*)WO;              j = i - 1048576; }
  else if (i < 2359296) { s = (const float4*)wk; d = (ushort4*)WQKV + 1048576;  j = i - 2097152; }
  else if (i < 2621440) { s = (const float4*)wv; d = (ushort4*)WQKV + 1310720;  j = i - 2359296; }
  else                  { s = (const float4*)x;  d = (ushort4*)XBF;             j = i - 2621440; }
  float4 v = s[j];
  ushort4 o;
  o.x = f32_to_bf16(v.x); o.y = f32_to_bf16(v.y);
  o.z = f32_to_bf16(v.z); o.w = f32_to_bf16(v.w);
  d[j] = o;
}

// ---------------- GEMM v2: C[M,N] = A[M,K] * W[N,K]^T ----------------
// MODE 0: plain f32 C.  MODE 1 (QKV, BM=256): Q-tiles (bn<8) -> bf16 QBF (ld 2048),
// KV-tiles (bn>=8) -> f32 XKV (ld 1024).
template <int BM, int MODE>
__global__ __launch_bounds__(512, 2) void gemm256_kernel(
    const unsigned short* __restrict__ A, const unsigned short* __restrict__ Bw,
    float* __restrict__ C, unsigned short* __restrict__ qbf_out,
    float* __restrict__ xkv_out, int M, int N, int K) {
  constexpr int ABYTES = BM * 128;
  constexpr int BBYTES = 256 * 128;
  constexpr int BUFB   = ABYTES + BBYTES;
  constexpr int ALOADS = BM / 64;
  constexpr int WROWS  = BM / 32;
  __shared__ __align__(16) char Lsh[2 * BUFB];

  const int tid = threadIdx.x;
  const int wid = tid >> 6, lane = tid & 63;
  const int lr = lane & 15, lg = lane >> 4;
  const int wr = wid >> 2, wc = wid & 3;
  const int bn = blockIdx.x, bm = blockIdx.y;
  const int x0 = lg * 16;

  f32x4 acc[WROWS][4] = {};

  const char* Ag = (const char*)A + (size_t)(bm * BM) * K * 2;
  const char* Bg = (const char*)Bw + (size_t)(bn * 256) * K * 2;

  int aoff[ALOADS], boff[4];
#pragma unroll
  for (int i = 0; i < ALOADS; ++i) {
    int lin = wid * (BM * 16) + i * 1024 + lane * 16;
    int grow = lin >> 7;
    int gcol = (lin & 127) ^ ((grow & 7) << 4);
    aoff[i] = grow * (K * 2) + gcol;
  }
#pragma unroll
  for (int i = 0; i < 4; ++i) {
    int lin = wid * 4096 + i * 1024 + lane * 16;
    int grow = lin >> 7;
    int gcol = (lin & 127) ^ ((grow & 7) << 4);
    boff[i] = grow * (K * 2) + gcol;
  }

  auto stage = [&](int s, int buf) {
    const int kb = s * 128;
    char* Lb = Lsh + buf * BUFB;
#pragma unroll
    for (int i = 0; i < ALOADS; ++i)
      gload_lds16(Ag + aoff[i] + kb, Lb + wid * (BM * 16) + i * 1024);
#pragma unroll
    for (int i = 0; i < 4; ++i)
      gload_lds16(Bg + boff[i] + kb, Lb + ABYTES + wid * 4096 + i * 1024);
  };

  auto kstep = [&](char* Lb) {
    bf16x8 bfr[4][2];
#pragma unroll
    for (int fc = 0; fc < 4; ++fc) {
      const int row = wc * 64 + fc * 16 + lr;
      const int base = ABYTES + row * 128;
      const int sw = (row & 7) << 4;
#pragma unroll
      for (int ks = 0; ks < 2; ++ks)
        bfr[fc][ks] = *reinterpret_cast<const bf16x8*>(Lb + base + ((ks * 64 + x0) ^ sw));
    }
#pragma unroll
    for (int q = 0; q < WROWS / 2; ++q) {
      bf16x8 af[2][2];
#pragma unroll
      for (int t = 0; t < 2; ++t) {
        const int row = wr * (BM / 2) + (2 * q + t) * 16 + lr;
        const int base = row * 128;
        const int sw = (row & 7) << 4;
#pragma unroll
        for (int ks = 0; ks < 2; ++ks)
          af[t][ks] = *reinterpret_cast<const bf16x8*>(Lb + base + ((ks * 64 + x0) ^ sw));
      }
      asm volatile("s_waitcnt lgkmcnt(0)" ::: "memory");
      __builtin_amdgcn_sched_barrier(0);
      __builtin_amdgcn_s_setprio(1);
#pragma unroll
      for (int t = 0; t < 2; ++t)
#pragma unroll
        for (int fc = 0; fc < 4; ++fc) {
          acc[2 * q + t][fc] = __builtin_amdgcn_mfma_f32_16x16x32_bf16(af[t][0], bfr[fc][0], acc[2 * q + t][fc], 0, 0, 0);
          acc[2 * q + t][fc] = __builtin_amdgcn_mfma_f32_16x16x32_bf16(af[t][1], bfr[fc][1], acc[2 * q + t][fc], 0, 0, 0);
        }
      __builtin_amdgcn_s_setprio(0);
    }
  };

  const int NST = K >> 6;
  stage(0, 0);
  for (int it = 0; it < NST / 2; ++it) {
    __builtin_amdgcn_s_barrier();
    stage(2 * it + 1, 1);
    if constexpr (BM == 256) asm volatile("s_waitcnt vmcnt(8)" ::: "memory");
    else                     asm volatile("s_waitcnt vmcnt(6)" ::: "memory");
    __builtin_amdgcn_s_barrier();
    kstep(Lsh);
    __builtin_amdgcn_s_barrier();
    if (it < NST / 2 - 1) {
      stage(2 * it + 2, 0);
      if constexpr (BM == 256) asm volatile("s_waitcnt vmcnt(8)" ::: "memory");
      else                     asm volatile("s_waitcnt vmcnt(6)" ::: "memory");
    } else {
      asm volatile("s_waitcnt vmcnt(0)" ::: "memory");
    }
    __builtin_amdgcn_s_barrier();
    kstep(Lsh + BUFB);
  }

  if constexpr (MODE == 0) {
#pragma unroll
    for (int fr = 0; fr < WROWS; ++fr) {
      const int m = bm * BM + wr * (BM / 2) + fr * 16 + lg * 4;
#pragma unroll
      for (int fc = 0; fc < 4; ++fc) {
        const int n = bn * 256 + wc * 64 + fc * 16 + lr;
#pragma unroll
        for (int r = 0; r < 4; ++r)
          C[(size_t)(m + r) * N + n] = acc[fr][fc][r];
      }
    }
  } else {
    if (bn < 8) {           // Q tiles -> bf16, ld 2048
#pragma unroll
      for (int fr = 0; fr < WROWS; ++fr) {
        const int m = bm * BM + wr * (BM / 2) + fr * 16 + lg * 4;
#pragma unroll
        for (int fc = 0; fc < 4; ++fc) {
          const int n = bn * 256 + wc * 64 + fc * 16 + lr;
#pragma unroll
          for (int r = 0; r < 4; ++r)
            qbf_out[(size_t)(m + r) * 2048 + n] = f32_to_bf16(acc[fr][fc][r]);
        }
      }
    } else {                // KV tiles -> f32 compact, ld 1024
#pragma unroll
      for (int fr = 0; fr < WROWS; ++fr) {
        const int m = bm * BM + wr * (BM / 2) + fr * 16 + lg * 4;
#pragma unroll
        for (int fc = 0; fc < 4; ++fc) {
          const int n = bn * 256 + wc * 64 + fc * 16 + lr - 2048;
#pragma unroll
          for (int r = 0; r < 4; ++r)
            xkv_out[(size_t)(m + r) * 1024 + n] = acc[fr][fc][r];
        }
      }
    }
  }
}

// ---------------- merged K-RoPE + V pass (reads compact XKV, ld 1024) ----------------
__global__ void kv_proc_kernel(const float* __restrict__ xkv, const float* __restrict__ fc,
                               const float* __restrict__ fs, unsigned short* __restrict__ kbf,
                               float* __restrict__ keys, unsigned short* __restrict__ vt,
                               float* __restrict__ values) {
  int bid = blockIdx.x;
  if (bid < 4096) {
    int idx = bid * 256 + threadIdx.x;        // pair index over (b,l,kv,i)
    int i = idx & 63;
    int kvh = (idx >> 6) & 3;
    int l = (idx >> 8) & 2047;
    int b = idx >> 19;
    float2 t = reinterpret_cast<const float2*>(xkv)[(size_t)(b * 2048 + l) * 512 + kvh * 64 + i];
    float c = fc[l * 64 + i], s = fs[l * 64 + i];
    float r0 = t.x * c - t.y * s;
    float r1 = t.x * s + t.y * c;
    int kidx = ((b * 4 + kvh) * 2048 + l) * 64 + i;
    ushort2 o; o.x = f32_to_bf16(r0); o.y = f32_to_bf16(r1);
    reinterpret_cast<ushort2*>(kbf)[kidx] = o;
    float2 f; f.x = r0; f.y = r1;
#pragma unroll
    for (int rep = 0; rep < 4; ++rep) {
      int h = kvh * 4 + rep;
      reinterpret_cast<float2*>(keys)[((b * 16 + h) * 2048 + l) * 64 + i] = f;
    }
  } else {
    int idx = (bid - 4096) * 256 + threadIdx.x; // element over (b,l,kv,d)
    int d = idx & 127;
    int kvh = (idx >> 7) & 3;
    int l = (idx >> 9) & 2047;
    int b = idx >> 20;
    float v = xkv[(size_t)(b * 2048 + l) * 1024 + 512 + kvh * 128 + d];
#pragma unroll
    for (int rep = 0; rep < 4; ++rep) {
      int h = kvh * 4 + rep;
      values[((size_t)(b * 16 + h) * 2048 + l) * 128 + d] = v;
    }
    vt[((size_t)(b * 4 + kvh) * 128 + d) * 2048 + l] = f32_to_bf16(v);
  }
}

// ---------------- causal flash attention v14 (R16 exact, measured 94.0us) ----------------
// 4 waves/block, wave owns 32 q-rows (2 x 16); KVBLK=64 staged in LDS (XOR swizzle,
// K rows pi-permuted -> in-lane cvt_pk P repack, no P LDS roundtrip). Swapped QK^T;
// defer-max (T13); final-step tail-skip; bf16 Q with fused RoPE; longest-first dispatch.
__global__ __launch_bounds__(256) void attn_kernel(
    const unsigned short* __restrict__ qbf, const float* __restrict__ fc,
    const float* __restrict__ fs, const unsigned short* __restrict__ kbf,
    const unsigned short* __restrict__ vt, unsigned short* __restrict__ obf) {
  __shared__ unsigned short Ks[64 * 128];      // [slot][d] rows 256B, XOR-swizzled, row-permuted
  __shared__ unsigned short Vs[128 * 64];      // [d][k] rows 128B, XOR-swizzled
  const int tid = threadIdx.x;
  const int w = tid >> 6, lane = tid & 63;
  const int lr = lane & 15, lg = lane >> 4;
  const int bid = blockIdx.x;
  const int qt = 15 - (bid >> 5);              // longest tiles dispatched first
  const int bh = bid & 31;
  const int b = bh >> 4, h = bh & 15, kv = h >> 2;
  const int q0 = qt * 128 + w * 32;
  const float ALPHA = 0.08838834764831845f;    // 1/sqrt(128), folded into Q
  const int swz = (lr & 7) << 4;

  // ---- fused RoPE Q-fragment build from bf16 Q ----
  bf16x8 qf[2][4];
#pragma unroll
  for (int t = 0; t < 2; ++t) {
    const int qrow = q0 + t * 16 + lr;
    const unsigned short* xqp = qbf + (size_t)(b * 2048 + qrow) * 2048 + h * 128;
    const float* fcp = fc + qrow * 64;
    const float* fsp = fs + qrow * 64;
#pragma unroll
    for (int s = 0; s < 4; ++s) {
      union { bf16x8 v8; unsigned short us[8]; } rw;
      rw.v8 = *reinterpret_cast<const bf16x8*>(xqp + s * 32 + lg * 8);
      float xv[8];
#pragma unroll
      for (int k = 0; k < 8; ++k) xv[k] = __uint_as_float(((unsigned)rw.us[k]) << 16);
      float4 c4 = *reinterpret_cast<const float4*>(fcp + s * 16 + lg * 4);
      float4 s4 = *reinterpret_cast<const float4*>(fsp + s * 16 + lg * 4);
      c4.x *= ALPHA; c4.y *= ALPHA; c4.z *= ALPHA; c4.w *= ALPHA;
      s4.x *= ALPHA; s4.y *= ALPHA; s4.z *= ALPHA; s4.w *= ALPHA;
      union { bf16x8 v8; unsigned u[4]; } uu;
      uu.u[0] = pack2(xv[0] * c4.x - xv[1] * s4.x, xv[0] * s4.x + xv[1] * c4.x);
      uu.u[1] = pack2(xv[2] * c4.y - xv[3] * s4.y, xv[2] * s4.y + xv[3] * c4.y);
      uu.u[2] = pack2(xv[4] * c4.z - xv[5] * s4.z, xv[4] * s4.z + xv[5] * c4.z);
      uu.u[3] = pack2(xv[6] * c4.w - xv[7] * s4.w, xv[6] * s4.w + xv[7] * c4.w);
      qf[t][s] = uu.v8;
    }
  }

  f32x4 acc[2][8] = {};
  float mrow[2] = {-1e30f, -1e30f}, lsum[2] = {0.f, 0.f};

  const char* kgbase = (const char*)(kbf + (size_t)(b * 4 + kv) * 2048 * 128);
  const char* vgbase = (const char*)(vt + (size_t)(b * 4 + kv) * 128 * 2048);

  int ksrc[4], vsrc[4];
#pragma unroll
  for (int i = 0; i < 4; ++i) {
    int p = w * 4096 + i * 1024 + lane * 16;
    int krow = p >> 8;
    int kperm = ((krow >> 5) << 5) + ((krow >> 4) & 1) + (((krow >> 2) & 3) << 3) + ((krow & 3) << 1);
    int kcol = (p & 255) ^ ((krow & 7) << 4);
    ksrc[i] = kperm * 256 + kcol;
    int drow = p >> 7;
    int dcol = (p & 127) ^ ((drow & 7) << 4);
    vsrc[i] = drow * 4096 + dcol;
  }

  const int nblocks = 2 * qt + 2;
  for (int j = 0; j < nblocks; ++j) {
    const int kb = j * 64;
    __syncthreads();
#pragma unroll
    for (int i = 0; i < 4; ++i) {
      gload_lds16(kgbase + (size_t)kb * 256 + ksrc[i], (char*)Ks + w * 4096 + i * 1024);
      gload_lds16(vgbase + (size_t)kb * 2 + vsrc[i], (char*)Vs + w * 4096 + i * 1024);
    }
    __syncthreads();
    if (j == nblocks - 1 && w < 2) continue;
    f32x4 sT[2][4];
#pragma unroll
    for (int c = 0; c < 4; ++c) {
      bf16x8 kf[4];
#pragma unroll
      for (int s = 0; s < 4; ++s)
        kf[s] = *reinterpret_cast<const bf16x8*>((char*)Ks + (((c * 16 + lr) * 256 + s * 64 + lg * 16) ^ swz));
      f32x4 t0 = {0.f, 0.f, 0.f, 0.f}, t1 = {0.f, 0.f, 0.f, 0.f};
#pragma unroll
      for (int s = 0; s < 4; ++s) {
        t0 = __builtin_amdgcn_mfma_f32_16x16x32_bf16(kf[s], qf[0][s], t0, 0, 0, 0);
        t1 = __builtin_amdgcn_mfma_f32_16x16x32_bf16(kf[s], qf[1][s], t1, 0, 0, 0);
      }
      sT[0][c] = t0; sT[1][c] = t1;
    }
    bf16x8 ptf[2][2];
#pragma unroll
    for (int t = 0; t < 2; ++t) {
      const int qrow = q0 + t * 16 + lr;
      float x[4][4];
      float mt = -1e30f;
#pragma unroll
      for (int c = 0; c < 4; ++c)
#pragma unroll
        for (int r = 0; r < 4; ++r) {
          int ka = kb + ((c >> 1) << 5) + (c & 1) + 8 * lg + 2 * r;
          float v = (ka <= qrow) ? sT[t][c][r] : -1e30f;
          x[c][r] = v;
          mt = fmaxf(mt, v);
        }
      mt = fmaxf(mt, __shfl_xor(mt, 16));
      mt = fmaxf(mt, __shfl_xor(mt, 32));
      const bool skip = __all(mt <= mrow[t] + 8.0f);
      float mnew, fac;
      if (skip) {
        mnew = mrow[t];
      } else {
        mnew = fmaxf(mrow[t], mt);
        fac = __expf(mrow[t] - mnew);
        mrow[t] = mnew;
      }
      float rs = 0.f;
      float pv[4][4];
#pragma unroll
      for (int c = 0; c < 4; ++c)
#pragma unroll
        for (int r = 0; r < 4; ++r) {
          float p = __expf(x[c][r] - mnew);
          pv[c][r] = p;
          rs += p;
        }
      rs += __shfl_xor(rs, 16);
      rs += __shfl_xor(rs, 32);
      if (skip) {
        lsum[t] += rs;
      } else {
        lsum[t] = lsum[t] * fac + rs;
#pragma unroll
        for (int dt = 0; dt < 8; ++dt)
#pragma unroll
          for (int r = 0; r < 4; ++r) acc[t][dt][r] *= fac;
      }
#pragma unroll
      for (int kk = 0; kk < 2; ++kk) {
        union { bf16x8 v8; unsigned u[4]; } uu;
#pragma unroll
        for (int wd = 0; wd < 4; ++wd)
          uu.u[wd] = pack2(pv[2 * kk][wd], pv[2 * kk + 1][wd]);
        ptf[t][kk] = uu.v8;
      }
    }
#pragma unroll
    for (int dt = 0; dt < 8; ++dt) {
      bf16x8 v0 = *reinterpret_cast<const bf16x8*>((char*)Vs + (((dt * 16 + lr) * 128 + lg * 16) ^ swz));
      bf16x8 v1 = *reinterpret_cast<const bf16x8*>((char*)Vs + (((dt * 16 + lr) * 128 + 64 + lg * 16) ^ swz));
      acc[0][dt] = __builtin_amdgcn_mfma_f32_16x16x32_bf16(v0, ptf[0][0], acc[0][dt], 0, 0, 0);
      acc[0][dt] = __builtin_amdgcn_mfma_f32_16x16x32_bf16(v1, ptf[0][1], acc[0][dt], 0, 0, 0);
      acc[1][dt] = __builtin_amdgcn_mfma_f32_16x16x32_bf16(v0, ptf[1][0], acc[1][dt], 0, 0, 0);
      acc[1][dt] = __builtin_amdgcn_mfma_f32_16x16x32_bf16(v1, ptf[1][1], acc[1][dt], 0, 0, 0);
    }
  }
#pragma unroll
  for (int t = 0; t < 2; ++t) {
    float inv = 1.0f / lsum[t];
#pragma unroll
    for (int dt = 0; dt < 8; ++dt) {
      ushort4 o;
      o.x = f32_to_bf16(acc[t][dt][0] * inv);
      o.y = f32_to_bf16(acc[t][dt][1] * inv);
      o.z = f32_to_bf16(acc[t][dt][2] * inv);
      o.w = f32_to_bf16(acc[t][dt][3] * inv);
      *reinterpret_cast<ushort4*>(obf + ((size_t)(b * 2048 + q0 + t * 16 + lr)) * 2048 + h * 128 + dt * 16 + lg * 4) = o;
    }
  }
}

// ---------------- host launch ----------------
extern "C" void kernel_launch(void* const* d_in, const int* in_sizes, int n_in,
                              void* d_out, int out_size, void* d_ws, size_t ws_size,
                              hipStream_t stream) {
  const float* x  = (const float*)d_in[0];
  const float* fc = (const float*)d_in[1];
  const float* fs = (const float*)d_in[2];
  const float* wq = (const float*)d_in[3];
  const float* wk = (const float*)d_in[4];
  const float* wv = (const float*)d_in[5];
  const float* wo = (const float*)d_in[6];

  float* out    = (float*)d_out;
  float* keys   = out + 8388608;
  float* values = out + 16777216;

  char* ws = (char*)d_ws;
  unsigned short* WQKV = (unsigned short*)(ws + 0);          // 12.6 MB: [wq;wk;wv] (3072 x 2048)
  unsigned short* WO   = (unsigned short*)(ws + 12582912);   // 8 MB
  unsigned short* XBF  = (unsigned short*)(ws + 20971520);   // 16 MB (reused as ATT)
  unsigned short* QBF  = (unsigned short*)(ws + 37748736);   // 16.8 MB bf16 Q (4096 x 2048)
  float*          XKV  = (float*)(ws + 54525952);            // 16.8 MB f32 KV (4096 x 1024)
  unsigned short* KBF  = (unsigned short*)(ws + 88080384);   // 4 MB
  unsigned short* VTB  = (unsigned short*)(ws + 92274688);   // 4 MB
  unsigned short* ATT  = XBF;                                // alias: XBF dead after projection

  cast_all_kernel<<<18432, 256, 0, stream>>>(wq, wo, wk, wv, x, WQKV, WO, XBF);

  // fused QKV projection (BM=256, 192 blocks, 1 round): Q->bf16 QBF, KV->f32 XKV
  gemm256_kernel<256, 1><<<dim3(12, 16), 512, 0, stream>>>(
      XBF, WQKV, nullptr, QBF, XKV, 4096, 3072, 2048);

  kv_proc_kernel<<<12288, 256, 0, stream>>>(XKV, fc, fs, KBF, keys, VTB, values);

  attn_kernel<<<512, 256, 0, stream>>>(QBF, fc, fs, KBF, VTB, ATT);

  // output projection (128x256 tiles, 256 blocks -> full fill)
  gemm256_kernel<128, 0><<<dim3(8, 32), 512, 0, stream>>>(
      ATT, WO, out, nullptr, nullptr, 4096, 2048, 2048);
}